// Round 9
// baseline (703.325 us; speedup 1.0000x reference)
//
#include <hip/hip_runtime.h>
#include <hip/hip_bf16.h>
#include <math.h>

#define BDIM   8
#define TDIM   2048
#define DDIM   512
#define PDIM   8
#define NTOK   (BDIM * TDIM)        // 16384
#define KDIM   (DDIM * PDIM)        // 4096
#define EPSF   1e-6f

typedef __attribute__((ext_vector_type(4))) float floatx4;
typedef __attribute__((ext_vector_type(8))) _Float16 half8;
typedef __attribute__((ext_vector_type(2))) _Float16 half2v;

// async global->LDS, 16 bytes per lane (dest must be base + lane*16)
__device__ __forceinline__ void gload_lds16(const void* g, void* l) {
    __builtin_amdgcn_global_load_lds(
        (const __attribute__((address_space(1))) unsigned int*)g,
        (__attribute__((address_space(3))) unsigned int*)l, 16, 0, 0);
}

// ================= prep (all 5 APL layers, hoisted) =================
__global__ void prep_prmh_kernel(const float* p0, const float* p1,
                                 const float* p2, const float* p3,
                                 const float* p4,
                                 unsigned short* __restrict__ prmh) {
    int layer = blockIdx.x;
    int i = threadIdx.x;  // 0..511
    const float* pts = layer == 0 ? p0 : layer == 1 ? p1 : layer == 2 ? p2
                     : layer == 3 ? p3 : p4;
    unsigned short* dst = prmh + (size_t)layer * DDIM * 16 + (size_t)i * 16;
    _Float16 invh[8], ofsh[8];
    invh[0] = (_Float16)0.f; ofsh[0] = (_Float16)1.f;
    #pragma unroll
    for (int p = 1; p < 8; ++p) {
        float a = pts[i * 8 + p - 1];
        float b = pts[i * 8 + p];
        float inv = 1.0f / (b - a);
        invh[p] = (_Float16)inv;
        ofsh[p] = (_Float16)(-a * inv);
    }
    *(uint4*)(dst)     = *(const uint4*)invh;
    *(uint4*)(dst + 8) = *(const uint4*)ofsh;
}

// W -> fp16, first-differenced, k-octet-interleaved; p=0 col zeroed (bias)
__global__ void prep_wtt_kernel(const float* v0, const float* v1,
                                const float* v2, const float* v3,
                                const float* v4,
                                unsigned short* __restrict__ Wtt_all) {
    int layer = blockIdx.y;
    const float* v = layer == 0 ? v0 : layer == 1 ? v1 : layer == 2 ? v2
                   : layer == 3 ? v3 : v4;
    unsigned short* Wtt = Wtt_all + (size_t)layer * KDIM * DDIM;
    int idx = blockIdx.x * blockDim.x + threadIdx.x;   // oct*512 + o
    int oct = idx >> 9, o = idx & 511;
    unsigned short f8[8];
    float prev = v[(size_t)(oct * 8) * DDIM + o];
    f8[0] = 0;
    #pragma unroll
    for (int p = 1; p < 8; ++p) {
        float cur = v[(size_t)(oct * 8 + p) * DDIM + o];
        float d = cur - prev;
        prev = cur;
        _Float16 hv = (_Float16)d;
        f8[p] = *reinterpret_cast<unsigned short*>(&hv);
    }
    *(uint4*)&Wtt[(size_t)idx * 8] = *(const uint4*)f8;
}

// bias[layer][o] = sum_i v[i][0][o]
__global__ void prep_bias_kernel(const float* v0, const float* v1,
                                 const float* v2, const float* v3,
                                 const float* v4,
                                 float* __restrict__ bias_all) {
    int layer = blockIdx.x;
    const float* v = layer == 0 ? v0 : layer == 1 ? v1 : layer == 2 ? v2
                   : layer == 3 ? v3 : v4;
    int o = threadIdx.x;
    float s = 0.f;
    for (int i = 0; i < DDIM; ++i) s += v[(size_t)i * PDIM * DDIM + o];
    bias_all[layer * DDIM + o] = s;
}

// ================= fused ramp-feature MFMA GEMM =================
// Round-8: wave tile widened 64x64 -> 64x128 (BN=256). Rationale from r7
// counters: MfmaUtil 37% == (3.4 waves/SIMD x 16 MFMA x 19.4cyc)/wall, i.e.
// the plateau is MFMA-per-wave DENSITY, not scheduling (LDS-BW, shape,
// latency, barrier-drain all refuted r2-r7). 32 MFMA/wave-iter doubles the
// per-SIMD matrix demand; A-frag reads, feat VALU and x fetch per output
// are halved (grid x 4 -> 2 removes duplication).
//   acc[4][8] = 128 VGPR -> launch_bounds(256,2), budget 256, ~210 needed.
//   LDS = As 16KB + Bs ring-of-3 48KB = 64KB -> 2 blocks/CU, grid 512.
//   Inner schedule identical to r7 (counted vmcnt(8) ring, As XOR swizzle,
//   setprio around MFMA cluster).
__launch_bounds__(256, 2)
__global__ void apl_gemm_mfma(const float* __restrict__ act,       // (N, D)
                              const unsigned short* __restrict__ WttA,
                              const unsigned short* __restrict__ WttB,
                              const unsigned short* __restrict__ prmA,
                              const unsigned short* __restrict__ prmB,
                              const float* __restrict__ biasA,
                              const float* __restrict__ biasB,
                              float* __restrict__ outA,
                              float* __restrict__ outB,
                              int sigA, int sigB) {
    __shared__ unsigned short As[2][128 * 32];      // 16KB, XOR-swizzled
    __shared__ unsigned short Bs[3][4 * 256 * 8];   // 48KB ring [buf][oct][o][p]

    const int zi = blockIdx.z;
    const unsigned short* Wtt = zi ? WttB : WttA;
    const unsigned short* prm = zi ? prmB : prmA;
    const float* bias = zi ? biasB : biasA;
    float* out = zi ? outB : outA;
    const int sig = zi ? sigB : sigA;

    const int t = threadIdx.x;
    const int w = t >> 6, l = t & 63;
    const int o0 = blockIdx.x * 256, n0 = blockIdx.y * 128;
    const int wn = w & 1, wo = w >> 1;              // 2x2 wave grid
    const int lm = l & 15, lq = l >> 4;
    // permute staging roles by block parity to spread VALU across SIMDs
    const int pw = (w + ((blockIdx.x + blockIdx.y) & 1) * 2) & 3;

    const half2v h2zero = {(_Float16)0.f, (_Float16)0.f};
    const half2v h2one  = {(_Float16)1.f, (_Float16)1.f};

    floatx4 acc[4][8];
    #pragma unroll
    for (int a = 0; a < 4; ++a)
        #pragma unroll
        for (int b = 0; b < 8; ++b) acc[a][b] = (floatx4){0.f, 0.f, 0.f, 0.f};

    // role-specific bases (pw is wave-uniform)
    const int an = pw * 64 + l;                       // A-role row in tile
    const float* arow = act + (size_t)(n0 + an) * DDIM;
    const int achk = (an >> 1) & 3;                   // A write-swizzle key

    // feature compute + swizzled LDS write for 4 input dims starting at i0
    auto feat_write = [&](float4 xq, int i0, unsigned short* Adst) {
        float xs[4] = {xq.x, xq.y, xq.z, xq.w};
        #pragma unroll
        for (int j = 0; j < 4; ++j) {
            const unsigned short* pb = prm + (size_t)(i0 + j) * 16;
            uint4 iv = *(const uint4*)pb;        // 4x half2 inv
            uint4 ov = *(const uint4*)(pb + 8);  // 4x half2 ofs
            _Float16 xh = (_Float16)xs[j];
            half2v x2 = {xh, xh};
            unsigned int invw[4] = {iv.x, iv.y, iv.z, iv.w};
            unsigned int ofsw[4] = {ov.x, ov.y, ov.z, ov.w};
            unsigned int fw[4];
            #pragma unroll
            for (int pp = 0; pp < 4; ++pp) {
                half2v in2 = __builtin_bit_cast(half2v, invw[pp]);
                half2v of2 = __builtin_bit_cast(half2v, ofsw[pp]);
                half2v tt = x2 * in2 + of2;                 // v_pk_fma_f16
                tt = __builtin_elementwise_max(tt, h2zero);
                tt = __builtin_elementwise_min(tt, h2one);
                fw[pp] = __builtin_bit_cast(unsigned int, tt);
            }
            uint4 pk = {fw[0], fw[1], fw[2], fw[3]};
            *(uint4*)&Adst[an * 32 + (j ^ achk) * 8] = pk;  // XOR swizzle
        }
    };

    // B-role: wave (pw-2) covers cols (pw-2)*128 .. +127 of the 256-col
    // tile. 8 async 16B issues per k-tile: k -> oct k>>1, col-half k&1.
    auto b_issue = [&](int i0, unsigned short* Bdst) {
        const unsigned short* wbase =
            Wtt + (size_t)(o0 + (pw - 2) * 128 + l) * 8;
        unsigned short* db = Bdst + (pw - 2) * 1024 + l * 8;
        #pragma unroll
        for (int k = 0; k < 8; ++k)
            gload_lds16(wbase + (size_t)(i0 + (k >> 1)) * (DDIM * 8) + (k & 1) * 512,
                        db + (k >> 1) * 2048 + (k & 1) * 512);
    };

    // fragments + 32 MFMAs; A-read swizzle matches write (row bits only)
    const int rchk = lq ^ ((lm >> 1) & 3);
    auto mfma_tile = [&](const unsigned short* Ac, const unsigned short* Bc) {
        half8 af[4], bfr[8];
        #pragma unroll
        for (int tn = 0; tn < 4; ++tn) {
            int row = wn * 64 + tn * 16 + lm;
            af[tn] = *(const half8*)&Ac[row * 32 + rchk * 8];
        }
        #pragma unroll
        for (int to = 0; to < 8; ++to)
            bfr[to] = *(const half8*)&Bc[lq * 2048 + (wo * 128 + to * 16 + lm) * 8];
        __builtin_amdgcn_s_setprio(1);
        #pragma unroll
        for (int tn = 0; tn < 4; ++tn)
            #pragma unroll
            for (int to = 0; to < 8; ++to)
                acc[tn][to] = __builtin_amdgcn_mfma_f32_16x16x32_f16(
                    af[tn], bfr[to], acc[tn][to], 0, 0, 0);
        __builtin_amdgcn_s_setprio(0);
    };

    const int NIT = KDIM / 32;   // 128 k-tiles

    // -------- prologue: A(0) + B(0),B(1); wait B(0) only --------
    if (pw < 2) {
        float4 xq0 = *(const float4*)&arow[0];
        feat_write(xq0, 0, As[0]);
    } else {
        b_issue(0, Bs[0]);
        b_issue(4, Bs[1]);
    }
    asm volatile("s_waitcnt vmcnt(8) lgkmcnt(0)" ::: "memory");
    __builtin_amdgcn_sched_barrier(0);
    __builtin_amdgcn_s_barrier();
    __builtin_amdgcn_sched_barrier(0);

    // ---- main loop: issue B(t+2),x(t+1) | MFMA(t) | feat(t+1) |
    //      wait vmcnt(8) [B(t+1) landed, B(t+2) in flight] + barrier ----
    for (int iter = 0; iter < NIT - 2; ++iter) {
        const int cur = iter & 1;

        float4 xq;
        if (pw < 2) {
            xq = *(const float4*)&arow[(iter + 1) * 4];
        } else {
            b_issue((iter + 2) * 4, Bs[(iter + 2) % 3]);
        }

        mfma_tile(As[cur], Bs[iter % 3]);
        __builtin_amdgcn_sched_barrier(0);        // keep prm loads below MFMAs

        if (pw < 2) feat_write(xq, (iter + 1) * 4, As[cur ^ 1]);

        asm volatile("s_waitcnt vmcnt(8) lgkmcnt(0)" ::: "memory");
        __builtin_amdgcn_sched_barrier(0);
        __builtin_amdgcn_s_barrier();
        __builtin_amdgcn_sched_barrier(0);
    }

    // ---- tail iter NIT-2: no new B issue; full drain for B(NIT-1) ----
    {
        const int iter = NIT - 2;                 // 126, cur = 0
        const int cur = iter & 1;
        float4 xq;
        if (pw < 2) xq = *(const float4*)&arow[(iter + 1) * 4];
        mfma_tile(As[cur], Bs[iter % 3]);
        __builtin_amdgcn_sched_barrier(0);
        if (pw < 2) feat_write(xq, (iter + 1) * 4, As[cur ^ 1]);
        __syncthreads();                          // vmcnt(0)+lgkmcnt(0)+bar
    }
    // final k-tile 127: As[1], Bs[127%3 = 1]
    mfma_tile(As[(NIT - 1) & 1], Bs[(NIT - 1) % 3]);

    // epilogue: C/D layout col=lane&15, row=(lane>>4)*4+reg; fp32 bias
    #pragma unroll
    for (int tn = 0; tn < 4; ++tn) {
        #pragma unroll
        for (int to = 0; to < 8; ++to) {
            int col = o0 + wo * 128 + to * 16 + lm;
            float bv = bias[col];
            #pragma unroll
            for (int rr = 0; rr < 4; ++rr) {
                int row = n0 + wn * 64 + tn * 16 + lq * 4 + rr;
                float val = acc[tn][to][rr] + bv;
                if (sig) val = 1.f / (1.f + __expf(-val));
                out[(size_t)row * DDIM + col] = val;
            }
        }
    }
}

// ================= recurrence: chunked linear scan =================
#define RC_CH 64
#define RC_L  (TDIM / RC_CH)      // 32
#define NCHAIN (BDIM * DDIM)      // 4096

__global__ void rec_pass1(const float* __restrict__ z, const float* __restrict__ hb,
                          float* __restrict__ Aout, float* __restrict__ Bout) {
    int tid = blockIdx.x * blockDim.x + threadIdx.x;
    int c = tid >> 12;
    int chain = tid & 4095;
    int b = chain >> 9, d = chain & 511;
    int base = ((b * TDIM) + c * RC_L) * DDIM + d;
    float ap = 1.f, h = 0.f;
    for (int s = 0; s < RC_L; ++s) {
        float zz = z[base];
        float hh = hb[base];
        float a = 1.f - zz;
        h = fmaf(a, h, zz * hh);
        ap *= a;
        base += DDIM;
    }
    Aout[c * NCHAIN + chain] = ap;
    Bout[c * NCHAIN + chain] = h;
}

__global__ void rec_pass2(const float* __restrict__ A, const float* __restrict__ Bv,
                          float* __restrict__ hstart) {
    int chain = blockIdx.x * blockDim.x + threadIdx.x;
    if (chain >= NCHAIN) return;
    float h = 0.f;
    #pragma unroll
    for (int c = 0; c < RC_CH; ++c) {
        hstart[c * NCHAIN + chain] = h;
        h = fmaf(A[c * NCHAIN + chain], h, Bv[c * NCHAIN + chain]);
    }
}

// pass3 fused with maxabs norm: one block per (chunk, batch), 512 threads.
__global__ void rec3_norm(const float* __restrict__ z, const float* __restrict__ hb,
                          const float* __restrict__ hstart,
                          float* __restrict__ out) {
    __shared__ float wmax[2][8];
    const int d = threadIdx.x;          // 0..511
    const int w = d >> 6, lane = d & 63;
    const int c = blockIdx.x;           // chunk
    const int b = blockIdx.y;           // batch
    const int chain = b * DDIM + d;
    float h = hstart[c * NCHAIN + chain];
    int base = ((b * TDIM) + c * RC_L) * DDIM + d;
    float zz = z[base];
    float hh = hb[base];
    for (int s = 0; s < RC_L; ++s) {
        float zn = 0.f, hn = 0.f;
        if (s + 1 < RC_L) {             // prefetch next step
            zn = z[base + DDIM];
            hn = hb[base + DDIM];
        }
        h = fmaf(1.f - zz, h, zz * hh);
        float m = fabsf(h);
        #pragma unroll
        for (int off = 32; off; off >>= 1) m = fmaxf(m, __shfl_xor(m, off, 64));
        if (lane == 0) wmax[s & 1][w] = m;
        __syncthreads();
        float M = wmax[s & 1][0];
        #pragma unroll
        for (int ww = 1; ww < 8; ++ww) M = fmaxf(M, wmax[s & 1][ww]);
        out[base] = h * (1.f / (M + EPSF));
        zz = zn; hh = hn; base += DDIM;
    }
}

// ================= orchestration =================
extern "C" void kernel_launch(void* const* d_in, const int* in_sizes, int n_in,
                              void* d_out, int out_size, void* d_ws, size_t ws_size,
                              hipStream_t stream) {
    const float* x   = (const float*)d_in[0];
    const float* pz0 = (const float*)d_in[1];
    const float* vz0 = (const float*)d_in[2];
    const float* ph0 = (const float*)d_in[3];
    const float* vh0 = (const float*)d_in[4];
    const float* pz1 = (const float*)d_in[5];
    const float* vz1 = (const float*)d_in[6];
    const float* ph1 = (const float*)d_in[7];
    const float* vh1 = (const float*)d_in[8];
    const float* po  = (const float*)d_in[9];
    const float* vo  = (const float*)d_in[10];

    float* out_r = (float*)d_out;
    float* h1_r  = out_r + (size_t)NTOK * DDIM;
    float* h2_r  = h1_r + (size_t)NTOK * DDIM;

    char* wp = (char*)d_ws;
    unsigned short* Wtt = (unsigned short*)wp; wp += (size_t)5 * KDIM * DDIM * 2;  // 20 MB
    unsigned short* prm = (unsigned short*)wp; wp += (size_t)5 * DDIM * 16 * 2;    // 80 KB
    float* bias = (float*)wp;  wp += 5 * DDIM * 4;
    float* Ab   = (float*)wp;  wp += RC_CH * NCHAIN * 4;
    float* Bb   = (float*)wp;  wp += RC_CH * NCHAIN * 4;
    float* hs   = (float*)wp;  wp += RC_CH * NCHAIN * 4;

    const size_t WS = (size_t)KDIM * DDIM;   // Wtt slot stride
    const size_t PS = (size_t)DDIM * 16;     // prm slot stride

    // -------- all param prep up front (layers: 0=z0 1=h0 2=z1 3=h1 4=out)
    prep_prmh_kernel<<<5, 512, 0, stream>>>(pz0, ph0, pz1, ph1, po, prm);
    prep_wtt_kernel<<<dim3((KDIM / 8) * DDIM / 256, 5), 256, 0, stream>>>(
        vz0, vh0, vz1, vh1, vo, Wtt);
    prep_bias_kernel<<<5, 512, 0, stream>>>(vz0, vh0, vz1, vh1, vo, bias);

    dim3 gemm2(DDIM / 256, NTOK / 128, 2);   // 512 blocks = 2/CU
    dim3 gemm1(DDIM / 256, NTOK / 128, 1);   // 256 blocks = 1/CU

    auto recur = [&](float* zb, float* hbuf, float* outb) {
        rec_pass1<<<(RC_CH * NCHAIN) / 256, 256, 0, stream>>>(zb, hbuf, Ab, Bb);
        rec_pass2<<<NCHAIN / 256, 256, 0, stream>>>(Ab, Bb, hs);
        rec3_norm<<<dim3(RC_CH, BDIM), 512, 0, stream>>>(zb, hbuf, hs, outb);
    };

    // layer 1: z -> out_r (sigmoid), h_bar -> h1_r; normalized h -> h1_r
    apl_gemm_mfma<<<gemm2, 256, 0, stream>>>(
        x, Wtt, Wtt + WS, prm, prm + PS, bias, bias + DDIM,
        out_r, h1_r, 1, 0);
    recur(out_r, h1_r, h1_r);

    // layer 2
    apl_gemm_mfma<<<gemm2, 256, 0, stream>>>(
        h1_r, Wtt + 2 * WS, Wtt + 3 * WS, prm + 2 * PS, prm + 3 * PS,
        bias + 2 * DDIM, bias + 3 * DDIM, out_r, h2_r, 1, 0);
    recur(out_r, h2_r, h2_r);

    // output APL
    apl_gemm_mfma<<<gemm1, 256, 0, stream>>>(
        h2_r, Wtt + 4 * WS, Wtt + 4 * WS, prm + 4 * PS, prm + 4 * PS,
        bias + 4 * DDIM, bias + 4 * DDIM, out_r, out_r, 0, 0);
}

// Round 10
// 676.489 us; speedup vs baseline: 1.0397x; 1.0397x over previous
//
#include <hip/hip_runtime.h>
#include <hip/hip_bf16.h>
#include <math.h>

#define BDIM   8
#define TDIM   2048
#define DDIM   512
#define PDIM   8
#define NTOK   (BDIM * TDIM)        // 16384
#define KDIM   (DDIM * PDIM)        // 4096
#define EPSF   1e-6f

typedef __attribute__((ext_vector_type(4))) float floatx4;
typedef __attribute__((ext_vector_type(8))) _Float16 half8;
typedef __attribute__((ext_vector_type(2))) _Float16 half2v;

// async global->LDS, 16 bytes per lane (dest must be base + lane*16)
__device__ __forceinline__ void gload_lds16(const void* g, void* l) {
    __builtin_amdgcn_global_load_lds(
        (const __attribute__((address_space(1))) unsigned int*)g,
        (__attribute__((address_space(3))) unsigned int*)l, 16, 0, 0);
}

// ================= prep (all 5 APL layers, hoisted) =================
__global__ void prep_prmh_kernel(const float* p0, const float* p1,
                                 const float* p2, const float* p3,
                                 const float* p4,
                                 unsigned short* __restrict__ prmh) {
    int layer = blockIdx.x;
    int i = threadIdx.x;  // 0..511
    const float* pts = layer == 0 ? p0 : layer == 1 ? p1 : layer == 2 ? p2
                     : layer == 3 ? p3 : p4;
    unsigned short* dst = prmh + (size_t)layer * DDIM * 16 + (size_t)i * 16;
    _Float16 invh[8], ofsh[8];
    invh[0] = (_Float16)0.f; ofsh[0] = (_Float16)1.f;
    #pragma unroll
    for (int p = 1; p < 8; ++p) {
        float a = pts[i * 8 + p - 1];
        float b = pts[i * 8 + p];
        float inv = 1.0f / (b - a);
        invh[p] = (_Float16)inv;
        ofsh[p] = (_Float16)(-a * inv);
    }
    *(uint4*)(dst)     = *(const uint4*)invh;
    *(uint4*)(dst + 8) = *(const uint4*)ofsh;
}

// W -> fp16, first-differenced, k-octet-interleaved; p=0 col zeroed (bias)
__global__ void prep_wtt_kernel(const float* v0, const float* v1,
                                const float* v2, const float* v3,
                                const float* v4,
                                unsigned short* __restrict__ Wtt_all) {
    int layer = blockIdx.y;
    const float* v = layer == 0 ? v0 : layer == 1 ? v1 : layer == 2 ? v2
                   : layer == 3 ? v3 : v4;
    unsigned short* Wtt = Wtt_all + (size_t)layer * KDIM * DDIM;
    int idx = blockIdx.x * blockDim.x + threadIdx.x;   // oct*512 + o
    int oct = idx >> 9, o = idx & 511;
    unsigned short f8[8];
    float prev = v[(size_t)(oct * 8) * DDIM + o];
    f8[0] = 0;
    #pragma unroll
    for (int p = 1; p < 8; ++p) {
        float cur = v[(size_t)(oct * 8 + p) * DDIM + o];
        float d = cur - prev;
        prev = cur;
        _Float16 hv = (_Float16)d;
        f8[p] = *reinterpret_cast<unsigned short*>(&hv);
    }
    *(uint4*)&Wtt[(size_t)idx * 8] = *(const uint4*)f8;
}

// bias[layer][o] = sum_i v[i][0][o]
__global__ void prep_bias_kernel(const float* v0, const float* v1,
                                 const float* v2, const float* v3,
                                 const float* v4,
                                 float* __restrict__ bias_all) {
    int layer = blockIdx.x;
    const float* v = layer == 0 ? v0 : layer == 1 ? v1 : layer == 2 ? v2
                   : layer == 3 ? v3 : v4;
    int o = threadIdx.x;
    float s = 0.f;
    for (int i = 0; i < DDIM; ++i) s += v[(size_t)i * PDIM * DDIM + o];
    bias_all[layer * DDIM + o] = s;
}

// ================= fused ramp-feature MFMA GEMM =================
// Round-10: r9 kernel + XCD-partitioned 1D grid. r2-r9 counters showed the
// wall is invariant (~3000 cyc/iter) across tile/occupancy/prefetch: the
// resident blocks stream 32KB/iter/CU of Wtt at the measured 6.7 TB/s --
// the L3 ceiling. Cause: gemm2's B working set (2 layers x 4MB) exceeds the
// 4MB per-XCD L2, and default round-robin dispatch (x fastest) hands every
// XCD blocks of every (x,z) combo -> L2 thrash -> B served from L3.
// Fix: 1D grid, decode so bid%8 (the XCD, m09 round-robin) pins one (x,z)
// per XCD -> per-XCD B slice = 256 cols x 4096 x 2B = 2MB, L2-resident.
// Grid 512 = exactly 2 blocks/CU (stable mapping); CU-sharing blocks get
// the SAME slice. After this, B-from-L2 ~585 cyc/iter < MFMA 1242 cyc.
__launch_bounds__(256, 2)
__global__ void apl_gemm_mfma(const float* __restrict__ act,       // (N, D)
                              const unsigned short* __restrict__ WttA,
                              const unsigned short* __restrict__ WttB,
                              const unsigned short* __restrict__ prmA,
                              const unsigned short* __restrict__ prmB,
                              const float* __restrict__ biasA,
                              const float* __restrict__ biasB,
                              float* __restrict__ outA,
                              float* __restrict__ outB,
                              int sigA, int sigB, int nz) {
    __shared__ unsigned short As[2][128 * 32];      // 16KB, XOR-swizzled
    __shared__ unsigned short Bs[3][4 * 256 * 8];   // 48KB ring [buf][oct][o][p]

    // ---- XCD-partitioned decode: bid%8 fixes (x,z) ----
    const int bid = blockIdx.x;
    const int xcd = bid & 7, j = bid >> 3;
    int bx, by, zi;
    if (nz == 2) {            // gemm2: 512 blocks, 4 (x,z) combos x 2 XCDs
        bx = xcd & 1; zi = (xcd >> 1) & 1; by = (j << 1) | (xcd >> 2);
    } else {                  // gemm1: 256 blocks, 2 x-combos x 4 XCDs
        bx = xcd & 1; zi = 0; by = (j << 2) | (xcd >> 1);
    }

    const unsigned short* Wtt = zi ? WttB : WttA;
    const unsigned short* prm = zi ? prmB : prmA;
    const float* bias = zi ? biasB : biasA;
    float* out = zi ? outB : outA;
    const int sig = zi ? sigB : sigA;

    const int t = threadIdx.x;
    const int w = t >> 6, l = t & 63;
    const int o0 = bx * 256, n0 = by * 128;
    const int wn = w & 1, wo = w >> 1;              // 2x2 wave grid
    const int lm = l & 15, lq = l >> 4;
    // permute staging roles by block parity to spread VALU across SIMDs
    const int pw = (w + ((bx + by) & 1) * 2) & 3;

    const half2v h2zero = {(_Float16)0.f, (_Float16)0.f};
    const half2v h2one  = {(_Float16)1.f, (_Float16)1.f};

    floatx4 acc[4][8];
    #pragma unroll
    for (int a = 0; a < 4; ++a)
        #pragma unroll
        for (int b = 0; b < 8; ++b) acc[a][b] = (floatx4){0.f, 0.f, 0.f, 0.f};

    // role-specific bases (pw is wave-uniform)
    const int an = pw * 64 + l;                       // A-role row in tile
    const float* arow = act + (size_t)(n0 + an) * DDIM;
    const int achk = (an >> 1) & 3;                   // A write-swizzle key

    // feature compute + swizzled LDS write for 4 input dims starting at i0
    auto feat_write = [&](float4 xq, int i0, unsigned short* Adst) {
        float xs[4] = {xq.x, xq.y, xq.z, xq.w};
        #pragma unroll
        for (int jj = 0; jj < 4; ++jj) {
            const unsigned short* pb = prm + (size_t)(i0 + jj) * 16;
            uint4 iv = *(const uint4*)pb;        // 4x half2 inv
            uint4 ov = *(const uint4*)(pb + 8);  // 4x half2 ofs
            _Float16 xh = (_Float16)xs[jj];
            half2v x2 = {xh, xh};
            unsigned int invw[4] = {iv.x, iv.y, iv.z, iv.w};
            unsigned int ofsw[4] = {ov.x, ov.y, ov.z, ov.w};
            unsigned int fw[4];
            #pragma unroll
            for (int pp = 0; pp < 4; ++pp) {
                half2v in2 = __builtin_bit_cast(half2v, invw[pp]);
                half2v of2 = __builtin_bit_cast(half2v, ofsw[pp]);
                half2v tt = x2 * in2 + of2;                 // v_pk_fma_f16
                tt = __builtin_elementwise_max(tt, h2zero);
                tt = __builtin_elementwise_min(tt, h2one);
                fw[pp] = __builtin_bit_cast(unsigned int, tt);
            }
            uint4 pk = {fw[0], fw[1], fw[2], fw[3]};
            *(uint4*)&Adst[an * 32 + (jj ^ achk) * 8] = pk;  // XOR swizzle
        }
    };

    // B-role: wave (pw-2) covers cols (pw-2)*128 .. +127 of the 256-col
    // tile. 8 async 16B issues per k-tile: k -> oct k>>1, col-half k&1.
    auto b_issue = [&](int i0, unsigned short* Bdst) {
        const unsigned short* wbase =
            Wtt + (size_t)(o0 + (pw - 2) * 128 + l) * 8;
        unsigned short* db = Bdst + (pw - 2) * 1024 + l * 8;
        #pragma unroll
        for (int k = 0; k < 8; ++k)
            gload_lds16(wbase + (size_t)(i0 + (k >> 1)) * (DDIM * 8) + (k & 1) * 512,
                        db + (k >> 1) * 2048 + (k & 1) * 512);
    };

    // fragments + 32 MFMAs; A-read swizzle matches write (row bits only)
    const int rchk = lq ^ ((lm >> 1) & 3);
    auto mfma_tile = [&](const unsigned short* Ac, const unsigned short* Bc) {
        half8 af[4], bfr[8];
        #pragma unroll
        for (int tn = 0; tn < 4; ++tn) {
            int row = wn * 64 + tn * 16 + lm;
            af[tn] = *(const half8*)&Ac[row * 32 + rchk * 8];
        }
        #pragma unroll
        for (int to = 0; to < 8; ++to)
            bfr[to] = *(const half8*)&Bc[lq * 2048 + (wo * 128 + to * 16 + lm) * 8];
        __builtin_amdgcn_s_setprio(1);
        #pragma unroll
        for (int tn = 0; tn < 4; ++tn)
            #pragma unroll
            for (int to = 0; to < 8; ++to)
                acc[tn][to] = __builtin_amdgcn_mfma_f32_16x16x32_f16(
                    af[tn], bfr[to], acc[tn][to], 0, 0, 0);
        __builtin_amdgcn_s_setprio(0);
    };

    const int NIT = KDIM / 32;   // 128 k-tiles

    // -------- prologue: A(0) + B(0),B(1); wait B(0) only --------
    if (pw < 2) {
        float4 xq0 = *(const float4*)&arow[0];
        feat_write(xq0, 0, As[0]);
    } else {
        b_issue(0, Bs[0]);
        b_issue(4, Bs[1]);
    }
    asm volatile("s_waitcnt vmcnt(8) lgkmcnt(0)" ::: "memory");
    __builtin_amdgcn_sched_barrier(0);
    __builtin_amdgcn_s_barrier();
    __builtin_amdgcn_sched_barrier(0);

    // ---- main loop: issue B(t+2),x(t+1) | MFMA(t) | feat(t+1) |
    //      wait vmcnt(8) [B(t+1) landed, B(t+2) in flight] + barrier ----
    for (int iter = 0; iter < NIT - 2; ++iter) {
        const int cur = iter & 1;

        float4 xq;
        if (pw < 2) {
            xq = *(const float4*)&arow[(iter + 1) * 4];
        } else {
            b_issue((iter + 2) * 4, Bs[(iter + 2) % 3]);
        }

        mfma_tile(As[cur], Bs[iter % 3]);
        __builtin_amdgcn_sched_barrier(0);        // keep prm loads below MFMAs

        if (pw < 2) feat_write(xq, (iter + 1) * 4, As[cur ^ 1]);

        asm volatile("s_waitcnt vmcnt(8) lgkmcnt(0)" ::: "memory");
        __builtin_amdgcn_sched_barrier(0);
        __builtin_amdgcn_s_barrier();
        __builtin_amdgcn_sched_barrier(0);
    }

    // ---- tail iter NIT-2: no new B issue; full drain for B(NIT-1) ----
    {
        const int iter = NIT - 2;                 // 126, cur = 0
        const int cur = iter & 1;
        float4 xq;
        if (pw < 2) xq = *(const float4*)&arow[(iter + 1) * 4];
        mfma_tile(As[cur], Bs[iter % 3]);
        __builtin_amdgcn_sched_barrier(0);
        if (pw < 2) feat_write(xq, (iter + 1) * 4, As[cur ^ 1]);
        __syncthreads();                          // vmcnt(0)+lgkmcnt(0)+bar
    }
    // final k-tile 127: As[1], Bs[127%3 = 1]
    mfma_tile(As[(NIT - 1) & 1], Bs[(NIT - 1) % 3]);

    // epilogue: C/D layout col=lane&15, row=(lane>>4)*4+reg; fp32 bias
    #pragma unroll
    for (int tn = 0; tn < 4; ++tn) {
        #pragma unroll
        for (int to = 0; to < 8; ++to) {
            int col = o0 + wo * 128 + to * 16 + lm;
            float bv = bias[col];
            #pragma unroll
            for (int rr = 0; rr < 4; ++rr) {
                int row = n0 + wn * 64 + tn * 16 + lq * 4 + rr;
                float val = acc[tn][to][rr] + bv;
                if (sig) val = 1.f / (1.f + __expf(-val));
                out[(size_t)row * DDIM + col] = val;
            }
        }
    }
}

// ================= recurrence: chunked linear scan =================
#define RC_CH 64
#define RC_L  (TDIM / RC_CH)      // 32
#define NCHAIN (BDIM * DDIM)      // 4096

__global__ void rec_pass1(const float* __restrict__ z, const float* __restrict__ hb,
                          float* __restrict__ Aout, float* __restrict__ Bout) {
    int tid = blockIdx.x * blockDim.x + threadIdx.x;
    int c = tid >> 12;
    int chain = tid & 4095;
    int b = chain >> 9, d = chain & 511;
    int base = ((b * TDIM) + c * RC_L) * DDIM + d;
    float ap = 1.f, h = 0.f;
    for (int s = 0; s < RC_L; ++s) {
        float zz = z[base];
        float hh = hb[base];
        float a = 1.f - zz;
        h = fmaf(a, h, zz * hh);
        ap *= a;
        base += DDIM;
    }
    Aout[c * NCHAIN + chain] = ap;
    Bout[c * NCHAIN + chain] = h;
}

__global__ void rec_pass2(const float* __restrict__ A, const float* __restrict__ Bv,
                          float* __restrict__ hstart) {
    int chain = blockIdx.x * blockDim.x + threadIdx.x;
    if (chain >= NCHAIN) return;
    float h = 0.f;
    #pragma unroll
    for (int c = 0; c < RC_CH; ++c) {
        hstart[c * NCHAIN + chain] = h;
        h = fmaf(A[c * NCHAIN + chain], h, Bv[c * NCHAIN + chain]);
    }
}

// pass3 fused with maxabs norm: one block per (chunk, batch), 512 threads.
__global__ void rec3_norm(const float* __restrict__ z, const float* __restrict__ hb,
                          const float* __restrict__ hstart,
                          float* __restrict__ out) {
    __shared__ float wmax[2][8];
    const int d = threadIdx.x;          // 0..511
    const int w = d >> 6, lane = d & 63;
    const int c = blockIdx.x;           // chunk
    const int b = blockIdx.y;           // batch
    const int chain = b * DDIM + d;
    float h = hstart[c * NCHAIN + chain];
    int base = ((b * TDIM) + c * RC_L) * DDIM + d;
    float zz = z[base];
    float hh = hb[base];
    for (int s = 0; s < RC_L; ++s) {
        float zn = 0.f, hn = 0.f;
        if (s + 1 < RC_L) {             // prefetch next step
            zn = z[base + DDIM];
            hn = hb[base + DDIM];
        }
        h = fmaf(1.f - zz, h, zz * hh);
        float m = fabsf(h);
        #pragma unroll
        for (int off = 32; off; off >>= 1) m = fmaxf(m, __shfl_xor(m, off, 64));
        if (lane == 0) wmax[s & 1][w] = m;
        __syncthreads();
        float M = wmax[s & 1][0];
        #pragma unroll
        for (int ww = 1; ww < 8; ++ww) M = fmaxf(M, wmax[s & 1][ww]);
        out[base] = h * (1.f / (M + EPSF));
        zz = zn; hh = hn; base += DDIM;
    }
}

// ================= orchestration =================
extern "C" void kernel_launch(void* const* d_in, const int* in_sizes, int n_in,
                              void* d_out, int out_size, void* d_ws, size_t ws_size,
                              hipStream_t stream) {
    const float* x   = (const float*)d_in[0];
    const float* pz0 = (const float*)d_in[1];
    const float* vz0 = (const float*)d_in[2];
    const float* ph0 = (const float*)d_in[3];
    const float* vh0 = (const float*)d_in[4];
    const float* pz1 = (const float*)d_in[5];
    const float* vz1 = (const float*)d_in[6];
    const float* ph1 = (const float*)d_in[7];
    const float* vh1 = (const float*)d_in[8];
    const float* po  = (const float*)d_in[9];
    const float* vo  = (const float*)d_in[10];

    float* out_r = (float*)d_out;
    float* h1_r  = out_r + (size_t)NTOK * DDIM;
    float* h2_r  = h1_r + (size_t)NTOK * DDIM;

    char* wp = (char*)d_ws;
    unsigned short* Wtt = (unsigned short*)wp; wp += (size_t)5 * KDIM * DDIM * 2;  // 20 MB
    unsigned short* prm = (unsigned short*)wp; wp += (size_t)5 * DDIM * 16 * 2;    // 80 KB
    float* bias = (float*)wp;  wp += 5 * DDIM * 4;
    float* Ab   = (float*)wp;  wp += RC_CH * NCHAIN * 4;
    float* Bb   = (float*)wp;  wp += RC_CH * NCHAIN * 4;
    float* hs   = (float*)wp;  wp += RC_CH * NCHAIN * 4;

    const size_t WS = (size_t)KDIM * DDIM;   // Wtt slot stride
    const size_t PS = (size_t)DDIM * 16;     // prm slot stride

    // -------- all param prep up front (layers: 0=z0 1=h0 2=z1 3=h1 4=out)
    prep_prmh_kernel<<<5, 512, 0, stream>>>(pz0, ph0, pz1, ph1, po, prm);
    prep_wtt_kernel<<<dim3((KDIM / 8) * DDIM / 256, 5), 256, 0, stream>>>(
        vz0, vh0, vz1, vh1, vo, Wtt);
    prep_bias_kernel<<<5, 512, 0, stream>>>(vz0, vh0, vz1, vh1, vo, bias);

    auto recur = [&](float* zb, float* hbuf, float* outb) {
        rec_pass1<<<(RC_CH * NCHAIN) / 256, 256, 0, stream>>>(zb, hbuf, Ab, Bb);
        rec_pass2<<<NCHAIN / 256, 256, 0, stream>>>(Ab, Bb, hs);
        rec3_norm<<<dim3(RC_CH, BDIM), 512, 0, stream>>>(zb, hbuf, hs, outb);
    };

    // layer 1: z -> out_r (sigmoid), h_bar -> h1_r; normalized h -> h1_r
    apl_gemm_mfma<<<512, 256, 0, stream>>>(
        x, Wtt, Wtt + WS, prm, prm + PS, bias, bias + DDIM,
        out_r, h1_r, 1, 0, 2);
    recur(out_r, h1_r, h1_r);

    // layer 2
    apl_gemm_mfma<<<512, 256, 0, stream>>>(
        h1_r, Wtt + 2 * WS, Wtt + 3 * WS, prm + 2 * PS, prm + 3 * PS,
        bias + 2 * DDIM, bias + 3 * DDIM, out_r, h2_r, 1, 0, 2);
    recur(out_r, h2_r, h2_r);

    // output APL
    apl_gemm_mfma<<<256, 256, 0, stream>>>(
        h2_r, Wtt + 4 * WS, Wtt + 4 * WS, prm + 4 * PS, prm + 4 * PS,
        bias + 4 * DDIM, bias + 4 * DDIM, out_r, out_r, 0, 0, 1);
}